// Round 3
// baseline (3659.752 us; speedup 1.0000x reference)
//
#include <hip/hip_runtime.h>
#include <hip/hip_bf16.h>
#include <cstdint>

#define S 2048
#define NH 32
#define HD 64
#define NJ 34              // 32 q heads + k + v
#define FUSED_N (NJ * HD)  // 2176
#define HDIM (NH * HD)     // 2048
#define HEAVY_K 128
#define RECENT_W 128
#define START_T 256

typedef __attribute__((ext_vector_type(8))) short short8;
typedef __attribute__((ext_vector_type(4))) float floatx4;

static __device__ __forceinline__ unsigned short f2bf(float f) {
    unsigned u = __float_as_uint(f);
    unsigned r = (u + 0x7FFF + ((u >> 16) & 1)) >> 16; // round-nearest-even
    return (unsigned short)r;
}
static __device__ __forceinline__ float bf2f(unsigned short b) {
    return __uint_as_float(((unsigned)b) << 16);
}

// ---------------------------------------------------------------------------
// GEMM: C[M x N] = A[M x K] * B[N x K]^T   (fp32)
// tile 128(M) x 64(N), K-step 16, 256 threads, 8x4 micro-tile
// ---------------------------------------------------------------------------
__global__ __launch_bounds__(256) void gemm_nt_kernel(const float* __restrict__ A,
                                                      const float* __restrict__ B,
                                                      float* __restrict__ C,
                                                      int K, int N)
{
    __shared__ float As[16][132];
    __shared__ float Bs[16][68];
    const int bm = blockIdx.y * 128;
    const int bn = blockIdx.x * 64;
    const int tid = threadIdx.x;
    const int tm = (tid >> 4) * 8;
    const int tn = (tid & 15) * 4;
    const int lr = tid >> 2;
    const int lk = (tid & 3) * 4;
    float acc[8][4] = {};
    const float* Ap0 = A + (size_t)(bm + lr) * K + lk;
    const float* Ap1 = Ap0 + (size_t)64 * K;
    const float* Bp  = B + (size_t)(bn + lr) * K + lk;
    for (int k0 = 0; k0 < K; k0 += 16) {
        float4 a0 = *(const float4*)(Ap0 + k0);
        float4 a1 = *(const float4*)(Ap1 + k0);
        float4 b0 = *(const float4*)(Bp + k0);
        As[lk + 0][lr] = a0.x; As[lk + 1][lr] = a0.y; As[lk + 2][lr] = a0.z; As[lk + 3][lr] = a0.w;
        As[lk + 0][lr + 64] = a1.x; As[lk + 1][lr + 64] = a1.y; As[lk + 2][lr + 64] = a1.z; As[lk + 3][lr + 64] = a1.w;
        Bs[lk + 0][lr] = b0.x; Bs[lk + 1][lr] = b0.y; Bs[lk + 2][lr] = b0.z; Bs[lk + 3][lr] = b0.w;
        __syncthreads();
#pragma unroll
        for (int kk = 0; kk < 16; ++kk) {
            float4 av0 = *(const float4*)&As[kk][tm];
            float4 av1 = *(const float4*)&As[kk][tm + 4];
            float4 bv  = *(const float4*)&Bs[kk][tn];
            float a8[8] = {av0.x, av0.y, av0.z, av0.w, av1.x, av1.y, av1.z, av1.w};
            float b4[4] = {bv.x, bv.y, bv.z, bv.w};
#pragma unroll
            for (int i = 0; i < 8; ++i)
#pragma unroll
                for (int j = 0; j < 4; ++j)
                    acc[i][j] += a8[i] * b4[j];
        }
        __syncthreads();
    }
#pragma unroll
    for (int i = 0; i < 8; ++i) {
        float4 r = make_float4(acc[i][0], acc[i][1], acc[i][2], acc[i][3]);
        *(float4*)(C + (size_t)(bm + tm + i) * N + (bn + tn)) = r;
    }
}

// ---------------------------------------------------------------------------
// RoPE + split fused -> qb [S][2048] bf16, kb [S][64] bf16, v [S][64] f32
// ---------------------------------------------------------------------------
__global__ __launch_bounds__(256) void rope_split_kernel(const float* __restrict__ fused,
                                                         unsigned short* __restrict__ qb,
                                                         unsigned short* __restrict__ kb,
                                                         float* __restrict__ v)
{
    int idx = blockIdx.x * 256 + threadIdx.x;
    const int total = S * NJ * HD;
    if (idx >= total) return;
    int t = idx / FUSED_N;
    int rem = idx - t * FUSED_N;
    int j = rem >> 6;
    int d = rem & 63;
    float x = fused[idx];
    if (j == 33) { v[t * HD + d] = x; return; }
    int i = d & 31;
    double inv = exp2(-(double)i * (13.287712379549449 / 32.0)); // 10000^(-i/32)
    double ang = (double)t * inv;
    float c  = (float)cos(ang);
    float sn = (float)sin(ang);
    float xo = fused[idx - d + ((d < 32) ? (d + 32) : (d - 32))];
    float rot = (d < 32) ? -xo : xo;
    unsigned short outv = f2bf(x * c + rot * sn);
    if (j == 32) kb[t * HD + d] = outv;
    else         qb[(size_t)t * HDIM + j * HD + d] = outv;
}

// ---------------------------------------------------------------------------
// z_kernel: Zinv[t][h] = 1 / sum_c exp(q_h[t]·k[c]/8)
// ---------------------------------------------------------------------------
__global__ __launch_bounds__(256) void z_kernel(const unsigned short* __restrict__ qb,
                                                const unsigned short* __restrict__ kb,
                                                float* __restrict__ zinv)
{
    const int t0 = blockIdx.x * 32;
    const int h  = blockIdx.y;
    const int w    = threadIdx.x >> 6;
    const int lane = threadIdx.x & 63;
    const int rsub = lane & 15;
    const int d0   = (lane >> 4) * 8;
    __shared__ float zl[4][32];

    short8 a[2][2];
#pragma unroll
    for (int mt = 0; mt < 2; ++mt) {
        const short8* ap = (const short8*)(qb + (size_t)(t0 + mt * 16 + rsub) * HDIM + h * HD + d0);
        a[mt][0] = ap[0];
        a[mt][1] = ap[4];
    }
    float z[2][4] = {};
    for (int nt = 0; nt < 32; ++nt) {
        const int c = w * 512 + nt * 16 + rsub;
        const short8* bp = (const short8*)(kb + (size_t)c * HD + d0);
        short8 b0 = bp[0];
        short8 b1 = bp[4];
#pragma unroll
        for (int mt = 0; mt < 2; ++mt) {
            floatx4 acc = {0.f, 0.f, 0.f, 0.f};
            acc = __builtin_amdgcn_mfma_f32_16x16x32_bf16(a[mt][0], b0, acc, 0, 0, 0);
            acc = __builtin_amdgcn_mfma_f32_16x16x32_bf16(a[mt][1], b1, acc, 0, 0, 0);
#pragma unroll
            for (int r = 0; r < 4; ++r) z[mt][r] += __expf(acc[r] * 0.125f);
        }
    }
#pragma unroll
    for (int mt = 0; mt < 2; ++mt)
#pragma unroll
        for (int r = 0; r < 4; ++r) {
            float zz = z[mt][r];
#pragma unroll
            for (int off = 1; off < 16; off <<= 1) zz += __shfl_xor(zz, off);
            z[mt][r] = zz;
        }
    if (rsub == 0) {
#pragma unroll
        for (int mt = 0; mt < 2; ++mt)
#pragma unroll
            for (int r = 0; r < 4; ++r)
                zl[w][mt * 16 + (lane >> 4) * 4 + r] = z[mt][r];
    }
    __syncthreads();
    if (threadIdx.x < 32) {
        float s = zl[0][threadIdx.x] + zl[1][threadIdx.x] + zl[2][threadIdx.x] + zl[3][threadIdx.x];
        zinv[(size_t)(t0 + threadIdx.x) * NH + h] = 1.0f / s;
    }
}

// ---------------------------------------------------------------------------
// pnorm_kernel: P[t][c] = sum_h exp(q_h[t]·k[c]/8) * zinv[t][h]
// ---------------------------------------------------------------------------
__global__ __launch_bounds__(256) void pnorm_kernel(const unsigned short* __restrict__ qb,
                                                    const unsigned short* __restrict__ kb,
                                                    const float* __restrict__ zinv,
                                                    float* __restrict__ P)
{
    const int t0 = blockIdx.y * 32;
    const int cb = blockIdx.x * 256;
    const int w    = threadIdx.x >> 6;
    const int lane = threadIdx.x & 63;
    const int rsub = lane & 15;
    const int d0   = (lane >> 4) * 8;
    __shared__ float zi[32][33];
    for (int i = threadIdx.x; i < 32 * 32; i += 256) {
        int row = i >> 5, hh = i & 31;
        zi[row][hh] = zinv[(size_t)(t0 + row) * NH + hh];
    }
    __syncthreads();

    float pacc[2][4][4] = {};
    for (int h = 0; h < NH; ++h) {
        short8 a[2][2];
#pragma unroll
        for (int mt = 0; mt < 2; ++mt) {
            const short8* ap = (const short8*)(qb + (size_t)(t0 + mt * 16 + rsub) * HDIM + h * HD + d0);
            a[mt][0] = ap[0];
            a[mt][1] = ap[4];
        }
        float zv[2][4];
#pragma unroll
        for (int mt = 0; mt < 2; ++mt)
#pragma unroll
            for (int r = 0; r < 4; ++r)
                zv[mt][r] = zi[mt * 16 + (lane >> 4) * 4 + r][h];
#pragma unroll
        for (int nt = 0; nt < 4; ++nt) {
            const int c = cb + w * 64 + nt * 16 + rsub;
            const short8* bp = (const short8*)(kb + (size_t)c * HD + d0);
            short8 b0 = bp[0];
            short8 b1 = bp[4];
#pragma unroll
            for (int mt = 0; mt < 2; ++mt) {
                floatx4 acc = {0.f, 0.f, 0.f, 0.f};
                acc = __builtin_amdgcn_mfma_f32_16x16x32_bf16(a[mt][0], b0, acc, 0, 0, 0);
                acc = __builtin_amdgcn_mfma_f32_16x16x32_bf16(a[mt][1], b1, acc, 0, 0, 0);
#pragma unroll
                for (int r = 0; r < 4; ++r)
                    pacc[mt][nt][r] += __expf(acc[r] * 0.125f) * zv[mt][r];
            }
        }
    }
#pragma unroll
    for (int mt = 0; mt < 2; ++mt)
#pragma unroll
        for (int nt = 0; nt < 4; ++nt)
#pragma unroll
            for (int r = 0; r < 4; ++r) {
                int row = t0 + mt * 16 + (lane >> 4) * 4 + r;
                int col = cb + w * 64 + nt * 16 + rsub;
                P[(size_t)row * S + col] = pacc[mt][nt][r];
            }
}

// ---------------------------------------------------------------------------
// acc_init: acc[c] = (c<256 ? sum_{t<256} P[t][c] : 0) + (c<=256 ? P[256][c] : 0)
// (rows 0..255 init + the whole t=256 scan step folded in)
// ---------------------------------------------------------------------------
__global__ __launch_bounds__(256) void acc_init_kernel(const float* __restrict__ P,
                                                       float* __restrict__ acc_init)
{
    int c = blockIdx.x * 256 + threadIdx.x;
    float s = 0.f;
    if (c < 256) {
        const float* p = P + c;
        float s0 = 0.f, s1 = 0.f, s2 = 0.f, s3 = 0.f;
#pragma unroll 4
        for (int t = 0; t < 256; t += 4) {
            s0 += p[(size_t)t * S];
            s1 += p[(size_t)(t + 1) * S];
            s2 += p[(size_t)(t + 2) * S];
            s3 += p[(size_t)(t + 3) * S];
        }
        s = (s0 + s1) + (s2 + s3);
    }
    if (c <= 256) s += P[(size_t)256 * S + c];
    acc_init[c] = s;
}

// ---------------------------------------------------------------------------
// Sequential heavy-hitter scan, 1 wave, barrier-free.
// P rows staged global->reg->LDS ring 3 steps ahead; acc + row access all LDS.
// Candidates at step t = previous 128 heavy cols + col (t-129): evict min
// (ties -> evict larger column, matching lax.top_k ascending-index tie-break).
// ---------------------------------------------------------------------------
__global__ void scan_kernel(const float* __restrict__ P,
                            const float* __restrict__ acc_init,
                            unsigned short* __restrict__ heavy)
{
    __shared__ float acc[S];       // 8 KB
    __shared__ float ring[4][S];   // 32 KB
    const int lane = threadIdx.x;  // 64 threads = 1 wave

    for (int c = lane; c < S; c += 64) acc[c] = acc_init[c];

    // heavy list for t = 256 is {0..127}
    heavy[START_T * HEAVY_K + lane] = (unsigned short)lane;
    heavy[START_T * HEAVY_K + 64 + lane] = (unsigned short)(lane + 64);

    int c0 = lane, c1 = lane + 64;

    float4 Rcur[8], Rnext[8];
    // prologue: rows 257,258 -> ring slots 1,2 ; row 259 -> Rcur
    {
        const float4* src = (const float4*)(P + (size_t)257 * S);
        float4 tmp[8];
#pragma unroll
        for (int i = 0; i < 8; ++i) tmp[i] = src[i * 64 + lane];
        float4* d1 = (float4*)ring[257 & 3];
#pragma unroll
        for (int i = 0; i < 8; ++i) d1[i * 64 + lane] = tmp[i];
        src = (const float4*)(P + (size_t)258 * S);
#pragma unroll
        for (int i = 0; i < 8; ++i) tmp[i] = src[i * 64 + lane];
        float4* d2 = (float4*)ring[258 & 3];
#pragma unroll
        for (int i = 0; i < 8; ++i) d2[i * 64 + lane] = tmp[i];
        src = (const float4*)(P + (size_t)259 * S);
#pragma unroll
        for (int i = 0; i < 8; ++i) Rcur[i] = src[i * 64 + lane];
    }

    for (int t = START_T + 1; t < S; ++t) {
        // (1) issue prefetch of row t+3 into registers (landed 3 iters later)
        {
            int pf = t + 3; if (pf > S - 1) pf = S - 1;
            const float4* src = (const float4*)(P + (size_t)pf * S);
#pragma unroll
            for (int i = 0; i < 8; ++i) Rnext[i] = src[i * 64 + lane];
        }
        // (2) stage Rcur (row t+2) into the ring
        {
            float4* dst = (float4*)ring[(t + 2) & 3];
#pragma unroll
            for (int i = 0; i < 8; ++i) dst[i * 64 + lane] = Rcur[i];
        }
        // (3) serial step t, all LDS
        const float* Pr = ring[t & 3];
        const int newc = t - 129;
        const int r0 = t - RECENT_W + lane;
        float v0 = acc[c0], v1 = acc[c1], nv = acc[newc];
        float pv0 = Pr[c0], pv1 = Pr[c1], pnew = Pr[newc];
        float pr0 = Pr[r0], pr1 = Pr[r0 + 64];
        float prt = Pr[t];

        float mv; int mc;
        if (v1 < v0 || (v1 == v0 && c1 > c0)) { mv = v1; mc = c1; }
        else                                  { mv = v0; mc = c0; }
#pragma unroll
        for (int off = 1; off < 64; off <<= 1) {
            float ov = __shfl_xor(mv, off);
            int   oc = __shfl_xor(mc, off);
            if (ov < mv || (ov == mv && oc > mc)) { mv = ov; mc = oc; }
        }
        bool evict_heavy = (mv < nv); // ties: new col (largest index) evicted
        if (evict_heavy) {
            if (c0 == mc)      { acc[c0] = 0.f; c0 = newc; pv0 = pnew; }
            else if (c1 == mc) { acc[c1] = 0.f; c1 = newc; pv1 = pnew; }
        } else if (lane == 0) {
            acc[newc] = 0.f;
        }
        acc[c0] += pv0;
        acc[c1] += pv1;
        acc[r0] += pr0;
        acc[r0 + 64] += pr1;
        if (lane == 0) acc[t] += prt;
        heavy[(size_t)t * HEAVY_K + lane] = (unsigned short)c0;
        heavy[(size_t)t * HEAVY_K + 64 + lane] = (unsigned short)c1;
#pragma unroll
        for (int i = 0; i < 8; ++i) Rcur[i] = Rnext[i];
    }
}

// ---------------------------------------------------------------------------
// Sparse masked attention: row t attends to {128 heavy} ∪ [t-128, t]
// ---------------------------------------------------------------------------
__global__ __launch_bounds__(256) void attn_kernel(const unsigned short* __restrict__ qb,
                                                   const unsigned short* __restrict__ kb,
                                                   const float* __restrict__ v,
                                                   const unsigned short* __restrict__ heavy,
                                                   float* __restrict__ attn)
{
    const int t = blockIdx.x;
    const int tid = threadIdx.x;
    __shared__ float qs[HDIM];
    __shared__ float sc[NH][258];
    __shared__ unsigned short cols[260];
    __shared__ float zpart[NH][8];
    __shared__ float zf[NH];
    const int cnt = (t < START_T) ? (t + 1) : 257;
    {
        const short8* qr = (const short8*)(qb + (size_t)t * HDIM);
        short8 qv = qr[tid];
#pragma unroll
        for (int j = 0; j < 8; ++j) qs[tid * 8 + j] = bf2f((unsigned short)qv[j]);
    }
    if (t < START_T) {
        for (int j = tid; j < cnt; j += 256) cols[j] = (unsigned short)j;
    } else {
        if (tid < 128) cols[tid] = heavy[(size_t)t * HEAVY_K + tid];
        else           cols[tid] = (unsigned short)(t - 256 + tid);
        if (tid == 0)  cols[256] = (unsigned short)t;
    }
    __syncthreads();
    {
        const int h = tid & 31;
        const float* qh = qs + h * HD;
        for (int j = tid >> 5; j < cnt; j += 8) {
            const short8* kc8 = (const short8*)(kb + (size_t)cols[j] * HD);
            float s = 0.f;
#pragma unroll
            for (int dq = 0; dq < 8; ++dq) {
                short8 kv = kc8[dq];
#pragma unroll
                for (int e = 0; e < 8; ++e)
                    s += qh[dq * 8 + e] * bf2f((unsigned short)kv[e]);
            }
            sc[h][j] = s * 0.125f;
        }
    }
    __syncthreads();
    {
        const int h2 = tid >> 3, sub = tid & 7;
        float z = 0.f;
        for (int j = sub; j < cnt; j += 8) {
            float e = __expf(sc[h2][j]);
            sc[h2][j] = e;
            z += e;
        }
        zpart[h2][sub] = z;
    }
    __syncthreads();
    if (tid < NH) {
        float z = 0.f;
#pragma unroll
        for (int s2 = 0; s2 < 8; ++s2) z += zpart[tid][s2];
        zf[tid] = 1.0f / z;
    }
    __syncthreads();
    {
        const int h2 = tid >> 3;
        const int dbase = (tid & 7) * 8;
        float o[8] = {0, 0, 0, 0, 0, 0, 0, 0};
        for (int j = 0; j < cnt; ++j) {
            float p = sc[h2][j];
            const float* vc = v + (size_t)cols[j] * HD + dbase;
            float4 va = *(const float4*)vc;
            float4 vb = *(const float4*)(vc + 4);
            o[0] += p * va.x; o[1] += p * va.y; o[2] += p * va.z; o[3] += p * va.w;
            o[4] += p * vb.x; o[5] += p * vb.y; o[6] += p * vb.z; o[7] += p * vb.w;
        }
        float zi = zf[h2];
        float* op = attn + (size_t)t * HDIM + h2 * HD + dbase;
        float4 ra = make_float4(o[0] * zi, o[1] * zi, o[2] * zi, o[3] * zi);
        float4 rb = make_float4(o[4] * zi, o[5] * zi, o[6] * zi, o[7] * zi);
        *(float4*)op = ra;
        *(float4*)(op + 4) = rb;
    }
}

// ---------------------------------------------------------------------------
extern "C" void kernel_launch(void* const* d_in, const int* in_sizes, int n_in,
                              void* d_out, int out_size, void* d_ws, size_t ws_size,
                              hipStream_t stream)
{
    (void)in_sizes; (void)n_in; (void)out_size; (void)ws_size;
    const float* hs      = (const float*)d_in[0];
    const float* w_qkv   = (const float*)d_in[1];
    const float* w_dense = (const float*)d_in[2];
    float* out = (float*)d_out;
    char* ws = (char*)d_ws;

    // workspace layout (bytes):
    //   [0, 17825792)            fused (2048x2176 f32) -> P (2048x2048 f32) -> attn (2048x2048 f32)
    //   [17825792, 26214400)     qb  bf16 [2048][2048]
    //   [26214400, 26476544)     kb  bf16 [2048][64]
    //   [26476544, 27000832)     v   f32  [2048][64]
    //   [27000832, 27262976)     zinv f32 [2048][32]
    //   [27262976, 27787264)     heavy ushort [2048][128]
    //   [27787264, 27795456)     acc_init f32 [2048]
    float* fused = (float*)(ws);
    float* P     = (float*)(ws);
    float* attn  = (float*)(ws);
    unsigned short* qb = (unsigned short*)(ws + 17825792);
    unsigned short* kb = (unsigned short*)(ws + 26214400);
    float* v           = (float*)(ws + 26476544);
    float* zinv        = (float*)(ws + 27000832);
    unsigned short* heavy = (unsigned short*)(ws + 27262976);
    float* acc_init       = (float*)(ws + 27787264);

    dim3 g1(FUSED_N / 64, S / 128);
    gemm_nt_kernel<<<g1, 256, 0, stream>>>(hs, w_qkv, fused, HDIM, FUSED_N);

    int total = S * NJ * HD;
    rope_split_kernel<<<(total + 255) / 256, 256, 0, stream>>>(fused, qb, kb, v);

    dim3 gz(S / 32, NH);
    z_kernel<<<gz, 256, 0, stream>>>(qb, kb, zinv);

    dim3 gp(S / 256, S / 32);
    pnorm_kernel<<<gp, 256, 0, stream>>>(qb, kb, zinv, P);

    acc_init_kernel<<<S / 256, 256, 0, stream>>>(P, acc_init);

    scan_kernel<<<1, 64, 0, stream>>>(P, acc_init, heavy);

    attn_kernel<<<S, 256, 0, stream>>>(qb, kb, v, heavy, attn);

    dim3 g2(HDIM / 64, S / 128);
    gemm_nt_kernel<<<g2, 256, 0, stream>>>(attn, w_dense, out, HDIM, HDIM);
}

// Round 4
// 2353.479 us; speedup vs baseline: 1.5550x; 1.5550x over previous
//
#include <hip/hip_runtime.h>
#include <hip/hip_bf16.h>
#include <cstdint>

#define S 2048
#define NH 32
#define HD 64
#define NJ 34              // 32 q heads + k + v
#define FUSED_N (NJ * HD)  // 2176
#define HDIM (NH * HD)     // 2048
#define HEAVY_K 128
#define RECENT_W 128
#define START_T 256
#define RING 8

typedef __attribute__((ext_vector_type(8))) short short8;
typedef __attribute__((ext_vector_type(4))) float floatx4;

static __device__ __forceinline__ unsigned short f2bf(float f) {
    unsigned u = __float_as_uint(f);
    unsigned r = (u + 0x7FFF + ((u >> 16) & 1)) >> 16; // round-nearest-even
    return (unsigned short)r;
}
static __device__ __forceinline__ float bf2f(unsigned short b) {
    return __uint_as_float(((unsigned)b) << 16);
}

// ---------------------------------------------------------------------------
// GEMM: C[M x N] = A[M x K] * B[N x K]^T   (fp32)
// tile 128(M) x 64(N), K-step 16, 256 threads, 8x4 micro-tile
// ---------------------------------------------------------------------------
__global__ __launch_bounds__(256) void gemm_nt_kernel(const float* __restrict__ A,
                                                      const float* __restrict__ B,
                                                      float* __restrict__ C,
                                                      int K, int N)
{
    __shared__ float As[16][132];
    __shared__ float Bs[16][68];
    const int bm = blockIdx.y * 128;
    const int bn = blockIdx.x * 64;
    const int tid = threadIdx.x;
    const int tm = (tid >> 4) * 8;
    const int tn = (tid & 15) * 4;
    const int lr = tid >> 2;
    const int lk = (tid & 3) * 4;
    float acc[8][4] = {};
    const float* Ap0 = A + (size_t)(bm + lr) * K + lk;
    const float* Ap1 = Ap0 + (size_t)64 * K;
    const float* Bp  = B + (size_t)(bn + lr) * K + lk;
    for (int k0 = 0; k0 < K; k0 += 16) {
        float4 a0 = *(const float4*)(Ap0 + k0);
        float4 a1 = *(const float4*)(Ap1 + k0);
        float4 b0 = *(const float4*)(Bp + k0);
        As[lk + 0][lr] = a0.x; As[lk + 1][lr] = a0.y; As[lk + 2][lr] = a0.z; As[lk + 3][lr] = a0.w;
        As[lk + 0][lr + 64] = a1.x; As[lk + 1][lr + 64] = a1.y; As[lk + 2][lr + 64] = a1.z; As[lk + 3][lr + 64] = a1.w;
        Bs[lk + 0][lr] = b0.x; Bs[lk + 1][lr] = b0.y; Bs[lk + 2][lr] = b0.z; Bs[lk + 3][lr] = b0.w;
        __syncthreads();
#pragma unroll
        for (int kk = 0; kk < 16; ++kk) {
            float4 av0 = *(const float4*)&As[kk][tm];
            float4 av1 = *(const float4*)&As[kk][tm + 4];
            float4 bv  = *(const float4*)&Bs[kk][tn];
            float a8[8] = {av0.x, av0.y, av0.z, av0.w, av1.x, av1.y, av1.z, av1.w};
            float b4[4] = {bv.x, bv.y, bv.z, bv.w};
#pragma unroll
            for (int i = 0; i < 8; ++i)
#pragma unroll
                for (int j = 0; j < 4; ++j)
                    acc[i][j] += a8[i] * b4[j];
        }
        __syncthreads();
    }
#pragma unroll
    for (int i = 0; i < 8; ++i) {
        float4 r = make_float4(acc[i][0], acc[i][1], acc[i][2], acc[i][3]);
        *(float4*)(C + (size_t)(bm + tm + i) * N + (bn + tn)) = r;
    }
}

// ---------------------------------------------------------------------------
// RoPE + split fused -> qb [S][2048] bf16, kb [S][64] bf16, v [S][64] f32
// ---------------------------------------------------------------------------
__global__ __launch_bounds__(256) void rope_split_kernel(const float* __restrict__ fused,
                                                         unsigned short* __restrict__ qb,
                                                         unsigned short* __restrict__ kb,
                                                         float* __restrict__ v)
{
    int idx = blockIdx.x * 256 + threadIdx.x;
    const int total = S * NJ * HD;
    if (idx >= total) return;
    int t = idx / FUSED_N;
    int rem = idx - t * FUSED_N;
    int j = rem >> 6;
    int d = rem & 63;
    float x = fused[idx];
    if (j == 33) { v[t * HD + d] = x; return; }
    int i = d & 31;
    double inv = exp2(-(double)i * (13.287712379549449 / 32.0)); // 10000^(-i/32)
    double ang = (double)t * inv;
    float c  = (float)cos(ang);
    float sn = (float)sin(ang);
    float xo = fused[idx - d + ((d < 32) ? (d + 32) : (d - 32))];
    float rot = (d < 32) ? -xo : xo;
    unsigned short outv = f2bf(x * c + rot * sn);
    if (j == 32) kb[t * HD + d] = outv;
    else         qb[(size_t)t * HDIM + j * HD + d] = outv;
}

// ---------------------------------------------------------------------------
// z_kernel: Zinv[t][h] = 1 / sum_c exp(q_h[t]·k[c]/8)
// ---------------------------------------------------------------------------
__global__ __launch_bounds__(256) void z_kernel(const unsigned short* __restrict__ qb,
                                                const unsigned short* __restrict__ kb,
                                                float* __restrict__ zinv)
{
    const int t0 = blockIdx.x * 32;
    const int h  = blockIdx.y;
    const int w    = threadIdx.x >> 6;
    const int lane = threadIdx.x & 63;
    const int rsub = lane & 15;
    const int d0   = (lane >> 4) * 8;
    __shared__ float zl[4][32];

    short8 a[2][2];
#pragma unroll
    for (int mt = 0; mt < 2; ++mt) {
        const short8* ap = (const short8*)(qb + (size_t)(t0 + mt * 16 + rsub) * HDIM + h * HD + d0);
        a[mt][0] = ap[0];
        a[mt][1] = ap[4];
    }
    float z[2][4] = {};
    for (int nt = 0; nt < 32; ++nt) {
        const int c = w * 512 + nt * 16 + rsub;
        const short8* bp = (const short8*)(kb + (size_t)c * HD + d0);
        short8 b0 = bp[0];
        short8 b1 = bp[4];
#pragma unroll
        for (int mt = 0; mt < 2; ++mt) {
            floatx4 acc = {0.f, 0.f, 0.f, 0.f};
            acc = __builtin_amdgcn_mfma_f32_16x16x32_bf16(a[mt][0], b0, acc, 0, 0, 0);
            acc = __builtin_amdgcn_mfma_f32_16x16x32_bf16(a[mt][1], b1, acc, 0, 0, 0);
#pragma unroll
            for (int r = 0; r < 4; ++r) z[mt][r] += __expf(acc[r] * 0.125f);
        }
    }
#pragma unroll
    for (int mt = 0; mt < 2; ++mt)
#pragma unroll
        for (int r = 0; r < 4; ++r) {
            float zz = z[mt][r];
#pragma unroll
            for (int off = 1; off < 16; off <<= 1) zz += __shfl_xor(zz, off);
            z[mt][r] = zz;
        }
    if (rsub == 0) {
#pragma unroll
        for (int mt = 0; mt < 2; ++mt)
#pragma unroll
            for (int r = 0; r < 4; ++r)
                zl[w][mt * 16 + (lane >> 4) * 4 + r] = z[mt][r];
    }
    __syncthreads();
    if (threadIdx.x < 32) {
        float s = zl[0][threadIdx.x] + zl[1][threadIdx.x] + zl[2][threadIdx.x] + zl[3][threadIdx.x];
        zinv[(size_t)(t0 + threadIdx.x) * NH + h] = 1.0f / s;
    }
}

// ---------------------------------------------------------------------------
// pnorm_kernel: P[t][c] = sum_h exp(q_h[t]·k[c]/8) * zinv[t][h]
// ---------------------------------------------------------------------------
__global__ __launch_bounds__(256) void pnorm_kernel(const unsigned short* __restrict__ qb,
                                                    const unsigned short* __restrict__ kb,
                                                    const float* __restrict__ zinv,
                                                    float* __restrict__ P)
{
    const int t0 = blockIdx.y * 32;
    const int cb = blockIdx.x * 256;
    const int w    = threadIdx.x >> 6;
    const int lane = threadIdx.x & 63;
    const int rsub = lane & 15;
    const int d0   = (lane >> 4) * 8;
    __shared__ float zi[32][33];
    for (int i = threadIdx.x; i < 32 * 32; i += 256) {
        int row = i >> 5, hh = i & 31;
        zi[row][hh] = zinv[(size_t)(t0 + row) * NH + hh];
    }
    __syncthreads();

    float pacc[2][4][4] = {};
    for (int h = 0; h < NH; ++h) {
        short8 a[2][2];
#pragma unroll
        for (int mt = 0; mt < 2; ++mt) {
            const short8* ap = (const short8*)(qb + (size_t)(t0 + mt * 16 + rsub) * HDIM + h * HD + d0);
            a[mt][0] = ap[0];
            a[mt][1] = ap[4];
        }
        float zv[2][4];
#pragma unroll
        for (int mt = 0; mt < 2; ++mt)
#pragma unroll
            for (int r = 0; r < 4; ++r)
                zv[mt][r] = zi[mt * 16 + (lane >> 4) * 4 + r][h];
#pragma unroll
        for (int nt = 0; nt < 4; ++nt) {
            const int c = cb + w * 64 + nt * 16 + rsub;
            const short8* bp = (const short8*)(kb + (size_t)c * HD + d0);
            short8 b0 = bp[0];
            short8 b1 = bp[4];
#pragma unroll
            for (int mt = 0; mt < 2; ++mt) {
                floatx4 acc = {0.f, 0.f, 0.f, 0.f};
                acc = __builtin_amdgcn_mfma_f32_16x16x32_bf16(a[mt][0], b0, acc, 0, 0, 0);
                acc = __builtin_amdgcn_mfma_f32_16x16x32_bf16(a[mt][1], b1, acc, 0, 0, 0);
#pragma unroll
                for (int r = 0; r < 4; ++r)
                    pacc[mt][nt][r] += __expf(acc[r] * 0.125f) * zv[mt][r];
            }
        }
    }
#pragma unroll
    for (int mt = 0; mt < 2; ++mt)
#pragma unroll
        for (int nt = 0; nt < 4; ++nt)
#pragma unroll
            for (int r = 0; r < 4; ++r) {
                int row = t0 + mt * 16 + (lane >> 4) * 4 + r;
                int col = cb + w * 64 + nt * 16 + rsub;
                P[(size_t)row * S + col] = pacc[mt][nt][r];
            }
}

// ---------------------------------------------------------------------------
// acc_init: acc[c] = (c<256 ? sum_{t<256} P[t][c] : 0) + (c<=256 ? P[256][c] : 0)
// ---------------------------------------------------------------------------
__global__ __launch_bounds__(256) void acc_init_kernel(const float* __restrict__ P,
                                                       float* __restrict__ acc_init)
{
    int c = blockIdx.x * 256 + threadIdx.x;
    float s = 0.f;
    if (c < 256) {
        const float* p = P + c;
        float s0 = 0.f, s1 = 0.f, s2 = 0.f, s3 = 0.f;
#pragma unroll 4
        for (int t = 0; t < 256; t += 4) {
            s0 += p[(size_t)t * S];
            s1 += p[(size_t)(t + 1) * S];
            s2 += p[(size_t)(t + 2) * S];
            s3 += p[(size_t)(t + 3) * S];
        }
        s = (s0 + s1) + (s2 + s3);
    }
    if (c <= 256) s += P[(size_t)256 * S + c];
    acc_init[c] = s;
}

// ---------------------------------------------------------------------------
// Sequential heavy-hitter scan, producer/consumer.
// wave 0: serial engine, heavy (col,val) pairs in REGISTERS (2/lane), zero
//         vmcnt waits; LDS used only for recent-window acc + row ring.
// waves 1..6: stage P rows into 8-slot LDS ring (global->reg->ds_write->flag).
// Heavy set and recent window are disjoint, so register-resident heavy values
// are exact. Eviction = min over 128 heavy vs acc[t-129] (tie: evict larger
// col / the new col), matching lax.top_k semantics.
// ---------------------------------------------------------------------------
__global__ __launch_bounds__(448) void scan_kernel(const float* __restrict__ P,
                                                   const float* __restrict__ acc_init,
                                                   unsigned short* __restrict__ heavy)
{
    __shared__ float accL[S];          // 8 KB
    __shared__ float ring[RING][S];    // 64 KB
    __shared__ int flags[RING];
    __shared__ int progress;

    const int tid  = threadIdx.x;
    const int wave = tid >> 6;
    const int lane = tid & 63;

    if (tid == 0) progress = START_T;
    if (tid < RING) flags[tid] = -1;
    __syncthreads();

    if (wave > 0) {
        // ---- producers: rows r = 256+wave, step 6  (covers 257..2047) ----
        volatile int* vprog = &progress;
        for (int r = START_T + wave; r < S; r += 6) {
            const float4* src = (const float4*)(P + (size_t)r * S);
            float4 buf[8];
#pragma unroll
            for (int i = 0; i < 8; ++i) buf[i] = src[i * 64 + lane];
            while (*vprog < r - RING) __builtin_amdgcn_s_sleep(2);
            float4* dst = (float4*)ring[r & (RING - 1)];
#pragma unroll
            for (int i = 0; i < 8; ++i) dst[i * 64 + lane] = buf[i];
            __threadfence_block();                 // drain ds_writes (wave-level)
            if (lane == 0) ((volatile int*)flags)[r & (RING - 1)] = r;
        }
        return;
    }

    // ---- wave 0: consumer / serial engine ----
    volatile int* vflag = flags;
    for (int c = lane; c < S; c += 64) accL[c] = acc_init[c];

    heavy[START_T * HEAVY_K + lane] = (unsigned short)lane;
    heavy[START_T * HEAVY_K + 64 + lane] = (unsigned short)(lane + 64);

    int   c0 = lane, c1 = lane + 64;
    float v0 = acc_init[lane], v1 = acc_init[lane + 64];

    // prologue prefetch for t = 257
    while (vflag[257 & (RING - 1)] != 257) __builtin_amdgcn_s_sleep(1);
    {
    }
    const float* R0 = ring[257 & (RING - 1)];
    float pv0 = R0[c0], pv1 = R0[c1];
    float pnew = R0[128];           // newc = 128
    float nv   = accL[128];
    float prt  = R0[257];
    int   r0i  = 257 - RECENT_W + lane;
    float pr0 = R0[r0i], pr1 = R0[r0i + 64];
    float ar0 = accL[r0i], ar1 = accL[r0i + 64];

    for (int t = START_T + 1; t < S; ++t) {
        // peek next row's flag early (verified at prefetch time)
        int fpeek = (t + 1 < S) ? vflag[(t + 1) & (RING - 1)] : 0;

        // ---- argmin over 128 register-resident heavy values ----
        float mv; int mc;
        if (v1 < v0 || (v1 == v0 && c1 > c0)) { mv = v1; mc = c1; }
        else                                  { mv = v0; mc = c0; }
#pragma unroll
        for (int off = 1; off < 64; off <<= 1) {
            float ov = __shfl_xor(mv, off);
            int   oc = __shfl_xor(mc, off);
            if (ov < mv || (ov == mv && oc > mc)) { mv = ov; mc = oc; }
        }
        const int newc = t - 129;
        bool evict = (mv < nv);     // tie -> new col dropped
        bool e0 = evict && (c0 == mc);
        bool e1 = evict && (c1 == mc);
        c0 = e0 ? newc : c0;
        v0 = e0 ? (nv + pnew) : (v0 + pv0);
        c1 = e1 ? newc : c1;
        v1 = e1 ? (nv + pnew) : (v1 + pv1);

        heavy[(size_t)t * HEAVY_K + lane]      = (unsigned short)c0;
        heavy[(size_t)t * HEAVY_K + 64 + lane] = (unsigned short)c1;

        // ---- recent-window accumulate (off the serial chain) ----
        const int r0c = t - RECENT_W + lane;
        accL[r0c]      = ar0 + pr0;
        accL[r0c + 64] = ar1 + pr1;
        if (lane == 0) accL[t] = prt;   // col t first touched at step t (was 0)

        // ---- prefetch for t+1 ----
        if (t + 1 < S) {
            const int tn = t + 1;
            if (lane == 0) *(volatile int*)&progress = t;
            if (fpeek != tn) {
                while (vflag[tn & (RING - 1)] != tn) __builtin_amdgcn_s_sleep(1);
            }
            const float* Rn = ring[tn & (RING - 1)];
            const int newcn = tn - 129;          // = t - 128
            pv0 = Rn[c0]; pv1 = Rn[c1];
            pnew = Rn[newcn];
            prt  = Rn[tn];
            const int r0n = tn - RECENT_W + lane;
            pr0 = Rn[r0n]; pr1 = Rn[r0n + 64];
            nv  = accL[newcn];                   // final after this step's writes
            ar0 = accL[r0n]; ar1 = accL[r0n + 64];
        }
    }
}

// ---------------------------------------------------------------------------
// Sparse masked attention: row t attends to {128 heavy} ∪ [t-128, t]
// ---------------------------------------------------------------------------
__global__ __launch_bounds__(256) void attn_kernel(const unsigned short* __restrict__ qb,
                                                   const unsigned short* __restrict__ kb,
                                                   const float* __restrict__ v,
                                                   const unsigned short* __restrict__ heavy,
                                                   float* __restrict__ attn)
{
    const int t = blockIdx.x;
    const int tid = threadIdx.x;
    __shared__ float qs[HDIM];
    __shared__ float sc[NH][258];
    __shared__ unsigned short cols[260];
    __shared__ float zpart[NH][8];
    __shared__ float zf[NH];
    const int cnt = (t < START_T) ? (t + 1) : 257;
    {
        const short8* qr = (const short8*)(qb + (size_t)t * HDIM);
        short8 qv = qr[tid];
#pragma unroll
        for (int j = 0; j < 8; ++j) qs[tid * 8 + j] = bf2f((unsigned short)qv[j]);
    }
    if (t < START_T) {
        for (int j = tid; j < cnt; j += 256) cols[j] = (unsigned short)j;
    } else {
        if (tid < 128) cols[tid] = heavy[(size_t)t * HEAVY_K + tid];
        else           cols[tid] = (unsigned short)(t - 256 + tid);
        if (tid == 0)  cols[256] = (unsigned short)t;
    }
    __syncthreads();
    {
        const int h = tid & 31;
        const float* qh = qs + h * HD;
        for (int j = tid >> 5; j < cnt; j += 8) {
            const short8* kc8 = (const short8*)(kb + (size_t)cols[j] * HD);
            float s = 0.f;
#pragma unroll
            for (int dq = 0; dq < 8; ++dq) {
                short8 kv = kc8[dq];
#pragma unroll
                for (int e = 0; e < 8; ++e)
                    s += qh[dq * 8 + e] * bf2f((unsigned short)kv[e]);
            }
            sc[h][j] = s * 0.125f;
        }
    }
    __syncthreads();
    {
        const int h2 = tid >> 3, sub = tid & 7;
        float z = 0.f;
        for (int j = sub; j < cnt; j += 8) {
            float e = __expf(sc[h2][j]);
            sc[h2][j] = e;
            z += e;
        }
        zpart[h2][sub] = z;
    }
    __syncthreads();
    if (tid < NH) {
        float z = 0.f;
#pragma unroll
        for (int s2 = 0; s2 < 8; ++s2) z += zpart[tid][s2];
        zf[tid] = 1.0f / z;
    }
    __syncthreads();
    {
        const int h2 = tid >> 3;
        const int dbase = (tid & 7) * 8;
        float o[8] = {0, 0, 0, 0, 0, 0, 0, 0};
        for (int j = 0; j < cnt; ++j) {
            float p = sc[h2][j];
            const float* vc = v + (size_t)cols[j] * HD + dbase;
            float4 va = *(const float4*)vc;
            float4 vb = *(const float4*)(vc + 4);
            o[0] += p * va.x; o[1] += p * va.y; o[2] += p * va.z; o[3] += p * va.w;
            o[4] += p * vb.x; o[5] += p * vb.y; o[6] += p * vb.z; o[7] += p * vb.w;
        }
        float zi = zf[h2];
        float* op = attn + (size_t)t * HDIM + h2 * HD + dbase;
        float4 ra = make_float4(o[0] * zi, o[1] * zi, o[2] * zi, o[3] * zi);
        float4 rb = make_float4(o[4] * zi, o[5] * zi, o[6] * zi, o[7] * zi);
        *(float4*)op = ra;
        *(float4*)(op + 4) = rb;
    }
}

// ---------------------------------------------------------------------------
extern "C" void kernel_launch(void* const* d_in, const int* in_sizes, int n_in,
                              void* d_out, int out_size, void* d_ws, size_t ws_size,
                              hipStream_t stream)
{
    (void)in_sizes; (void)n_in; (void)out_size; (void)ws_size;
    const float* hs      = (const float*)d_in[0];
    const float* w_qkv   = (const float*)d_in[1];
    const float* w_dense = (const float*)d_in[2];
    float* out = (float*)d_out;
    char* ws = (char*)d_ws;

    // workspace layout (bytes):
    //   [0, 17825792)            fused (2048x2176 f32) -> P (2048x2048 f32) -> attn (2048x2048 f32)
    //   [17825792, 26214400)     qb  bf16 [2048][2048]
    //   [26214400, 26476544)     kb  bf16 [2048][64]
    //   [26476544, 27000832)     v   f32  [2048][64]
    //   [27000832, 27262976)     zinv f32 [2048][32]
    //   [27262976, 27787264)     heavy ushort [2048][128]
    //   [27787264, 27795456)     acc_init f32 [2048]
    float* fused = (float*)(ws);
    float* P     = (float*)(ws);
    float* attn  = (float*)(ws);
    unsigned short* qb = (unsigned short*)(ws + 17825792);
    unsigned short* kb = (unsigned short*)(ws + 26214400);
    float* v           = (float*)(ws + 26476544);
    float* zinv        = (float*)(ws + 27000832);
    unsigned short* heavy = (unsigned short*)(ws + 27262976);
    float* acc_init       = (float*)(ws + 27787264);

    dim3 g1(FUSED_N / 64, S / 128);
    gemm_nt_kernel<<<g1, 256, 0, stream>>>(hs, w_qkv, fused, HDIM, FUSED_N);

    int total = S * NJ * HD;
    rope_split_kernel<<<(total + 255) / 256, 256, 0, stream>>>(fused, qb, kb, v);

    dim3 gz(S / 32, NH);
    z_kernel<<<gz, 256, 0, stream>>>(qb, kb, zinv);

    dim3 gp(S / 256, S / 32);
    pnorm_kernel<<<gp, 256, 0, stream>>>(qb, kb, zinv, P);

    acc_init_kernel<<<S / 256, 256, 0, stream>>>(P, acc_init);

    scan_kernel<<<1, 448, 0, stream>>>(P, acc_init, heavy);

    attn_kernel<<<S, 256, 0, stream>>>(qb, kb, v, heavy, attn);

    dim3 g2(HDIM / 64, S / 128);
    gemm_nt_kernel<<<g2, 256, 0, stream>>>(attn, w_dense, out, HDIM, HDIM);
}

// Round 5
// 1888.976 us; speedup vs baseline: 1.9374x; 1.2459x over previous
//
#include <hip/hip_runtime.h>
#include <hip/hip_bf16.h>
#include <cstdint>

#define S 2048
#define NH 32
#define HD 64
#define NJ 34              // 32 q heads + k + v
#define FUSED_N (NJ * HD)  // 2176
#define HDIM (NH * HD)     // 2048
#define HEAVY_K 128
#define RECENT_W 128
#define START_T 256

typedef __attribute__((ext_vector_type(8))) short short8;
typedef __attribute__((ext_vector_type(4))) float floatx4;

static __device__ __forceinline__ unsigned short f2bf(float f) {
    unsigned u = __float_as_uint(f);
    unsigned r = (u + 0x7FFF + ((u >> 16) & 1)) >> 16; // round-nearest-even
    return (unsigned short)r;
}
static __device__ __forceinline__ float bf2f(unsigned short b) {
    return __uint_as_float(((unsigned)b) << 16);
}

// ---------------------------------------------------------------------------
// GEMM: C[M x N] = A[M x K] * B[N x K]^T   (fp32)
// tile 128(M) x 64(N), K-step 16, 256 threads, 8x4 micro-tile
// ---------------------------------------------------------------------------
__global__ __launch_bounds__(256) void gemm_nt_kernel(const float* __restrict__ A,
                                                      const float* __restrict__ B,
                                                      float* __restrict__ C,
                                                      int K, int N)
{
    __shared__ float As[16][132];
    __shared__ float Bs[16][68];
    const int bm = blockIdx.y * 128;
    const int bn = blockIdx.x * 64;
    const int tid = threadIdx.x;
    const int tm = (tid >> 4) * 8;
    const int tn = (tid & 15) * 4;
    const int lr = tid >> 2;
    const int lk = (tid & 3) * 4;
    float acc[8][4] = {};
    const float* Ap0 = A + (size_t)(bm + lr) * K + lk;
    const float* Ap1 = Ap0 + (size_t)64 * K;
    const float* Bp  = B + (size_t)(bn + lr) * K + lk;
    for (int k0 = 0; k0 < K; k0 += 16) {
        float4 a0 = *(const float4*)(Ap0 + k0);
        float4 a1 = *(const float4*)(Ap1 + k0);
        float4 b0 = *(const float4*)(Bp + k0);
        As[lk + 0][lr] = a0.x; As[lk + 1][lr] = a0.y; As[lk + 2][lr] = a0.z; As[lk + 3][lr] = a0.w;
        As[lk + 0][lr + 64] = a1.x; As[lk + 1][lr + 64] = a1.y; As[lk + 2][lr + 64] = a1.z; As[lk + 3][lr + 64] = a1.w;
        Bs[lk + 0][lr] = b0.x; Bs[lk + 1][lr] = b0.y; Bs[lk + 2][lr] = b0.z; Bs[lk + 3][lr] = b0.w;
        __syncthreads();
#pragma unroll
        for (int kk = 0; kk < 16; ++kk) {
            float4 av0 = *(const float4*)&As[kk][tm];
            float4 av1 = *(const float4*)&As[kk][tm + 4];
            float4 bv  = *(const float4*)&Bs[kk][tn];
            float a8[8] = {av0.x, av0.y, av0.z, av0.w, av1.x, av1.y, av1.z, av1.w};
            float b4[4] = {bv.x, bv.y, bv.z, bv.w};
#pragma unroll
            for (int i = 0; i < 8; ++i)
#pragma unroll
                for (int j = 0; j < 4; ++j)
                    acc[i][j] += a8[i] * b4[j];
        }
        __syncthreads();
    }
#pragma unroll
    for (int i = 0; i < 8; ++i) {
        float4 r = make_float4(acc[i][0], acc[i][1], acc[i][2], acc[i][3]);
        *(float4*)(C + (size_t)(bm + tm + i) * N + (bn + tn)) = r;
    }
}

// ---------------------------------------------------------------------------
// RoPE + split fused -> qb [S][2048] bf16, kb [S][64] bf16, v [S][64] f32
// ---------------------------------------------------------------------------
__global__ __launch_bounds__(256) void rope_split_kernel(const float* __restrict__ fused,
                                                         unsigned short* __restrict__ qb,
                                                         unsigned short* __restrict__ kb,
                                                         float* __restrict__ v)
{
    int idx = blockIdx.x * 256 + threadIdx.x;
    const int total = S * NJ * HD;
    if (idx >= total) return;
    int t = idx / FUSED_N;
    int rem = idx - t * FUSED_N;
    int j = rem >> 6;
    int d = rem & 63;
    float x = fused[idx];
    if (j == 33) { v[t * HD + d] = x; return; }
    int i = d & 31;
    double inv = exp2(-(double)i * (13.287712379549449 / 32.0)); // 10000^(-i/32)
    double ang = (double)t * inv;
    float c  = (float)cos(ang);
    float sn = (float)sin(ang);
    float xo = fused[idx - d + ((d < 32) ? (d + 32) : (d - 32))];
    float rot = (d < 32) ? -xo : xo;
    unsigned short outv = f2bf(x * c + rot * sn);
    if (j == 32) kb[t * HD + d] = outv;
    else         qb[(size_t)t * HDIM + j * HD + d] = outv;
}

// ---------------------------------------------------------------------------
// z_kernel: Zinv[t][h] = 1 / sum_c exp(q_h[t]·k[c]/8)
// ---------------------------------------------------------------------------
__global__ __launch_bounds__(256) void z_kernel(const unsigned short* __restrict__ qb,
                                                const unsigned short* __restrict__ kb,
                                                float* __restrict__ zinv)
{
    const int t0 = blockIdx.x * 32;
    const int h  = blockIdx.y;
    const int w    = threadIdx.x >> 6;
    const int lane = threadIdx.x & 63;
    const int rsub = lane & 15;
    const int d0   = (lane >> 4) * 8;
    __shared__ float zl[4][32];

    short8 a[2][2];
#pragma unroll
    for (int mt = 0; mt < 2; ++mt) {
        const short8* ap = (const short8*)(qb + (size_t)(t0 + mt * 16 + rsub) * HDIM + h * HD + d0);
        a[mt][0] = ap[0];
        a[mt][1] = ap[4];
    }
    float z[2][4] = {};
    for (int nt = 0; nt < 32; ++nt) {
        const int c = w * 512 + nt * 16 + rsub;
        const short8* bp = (const short8*)(kb + (size_t)c * HD + d0);
        short8 b0 = bp[0];
        short8 b1 = bp[4];
#pragma unroll
        for (int mt = 0; mt < 2; ++mt) {
            floatx4 acc = {0.f, 0.f, 0.f, 0.f};
            acc = __builtin_amdgcn_mfma_f32_16x16x32_bf16(a[mt][0], b0, acc, 0, 0, 0);
            acc = __builtin_amdgcn_mfma_f32_16x16x32_bf16(a[mt][1], b1, acc, 0, 0, 0);
#pragma unroll
            for (int r = 0; r < 4; ++r) z[mt][r] += __expf(acc[r] * 0.125f);
        }
    }
#pragma unroll
    for (int mt = 0; mt < 2; ++mt)
#pragma unroll
        for (int r = 0; r < 4; ++r) {
            float zz = z[mt][r];
#pragma unroll
            for (int off = 1; off < 16; off <<= 1) zz += __shfl_xor(zz, off);
            z[mt][r] = zz;
        }
    if (rsub == 0) {
#pragma unroll
        for (int mt = 0; mt < 2; ++mt)
#pragma unroll
            for (int r = 0; r < 4; ++r)
                zl[w][mt * 16 + (lane >> 4) * 4 + r] = z[mt][r];
    }
    __syncthreads();
    if (threadIdx.x < 32) {
        float s = zl[0][threadIdx.x] + zl[1][threadIdx.x] + zl[2][threadIdx.x] + zl[3][threadIdx.x];
        zinv[(size_t)(t0 + threadIdx.x) * NH + h] = 1.0f / s;
    }
}

// ---------------------------------------------------------------------------
// pnorm_kernel: P[t][c] = sum_h exp(q_h[t]·k[c]/8) * zinv[t][h]
// ---------------------------------------------------------------------------
__global__ __launch_bounds__(256) void pnorm_kernel(const unsigned short* __restrict__ qb,
                                                    const unsigned short* __restrict__ kb,
                                                    const float* __restrict__ zinv,
                                                    float* __restrict__ P)
{
    const int t0 = blockIdx.y * 32;
    const int cb = blockIdx.x * 256;
    const int w    = threadIdx.x >> 6;
    const int lane = threadIdx.x & 63;
    const int rsub = lane & 15;
    const int d0   = (lane >> 4) * 8;
    __shared__ float zi[32][33];
    for (int i = threadIdx.x; i < 32 * 32; i += 256) {
        int row = i >> 5, hh = i & 31;
        zi[row][hh] = zinv[(size_t)(t0 + row) * NH + hh];
    }
    __syncthreads();

    float pacc[2][4][4] = {};
    for (int h = 0; h < NH; ++h) {
        short8 a[2][2];
#pragma unroll
        for (int mt = 0; mt < 2; ++mt) {
            const short8* ap = (const short8*)(qb + (size_t)(t0 + mt * 16 + rsub) * HDIM + h * HD + d0);
            a[mt][0] = ap[0];
            a[mt][1] = ap[4];
        }
        float zv[2][4];
#pragma unroll
        for (int mt = 0; mt < 2; ++mt)
#pragma unroll
            for (int r = 0; r < 4; ++r)
                zv[mt][r] = zi[mt * 16 + (lane >> 4) * 4 + r][h];
#pragma unroll
        for (int nt = 0; nt < 4; ++nt) {
            const int c = cb + w * 64 + nt * 16 + rsub;
            const short8* bp = (const short8*)(kb + (size_t)c * HD + d0);
            short8 b0 = bp[0];
            short8 b1 = bp[4];
#pragma unroll
            for (int mt = 0; mt < 2; ++mt) {
                floatx4 acc = {0.f, 0.f, 0.f, 0.f};
                acc = __builtin_amdgcn_mfma_f32_16x16x32_bf16(a[mt][0], b0, acc, 0, 0, 0);
                acc = __builtin_amdgcn_mfma_f32_16x16x32_bf16(a[mt][1], b1, acc, 0, 0, 0);
#pragma unroll
                for (int r = 0; r < 4; ++r)
                    pacc[mt][nt][r] += __expf(acc[r] * 0.125f) * zv[mt][r];
            }
        }
    }
#pragma unroll
    for (int mt = 0; mt < 2; ++mt)
#pragma unroll
        for (int nt = 0; nt < 4; ++nt)
#pragma unroll
            for (int r = 0; r < 4; ++r) {
                int row = t0 + mt * 16 + (lane >> 4) * 4 + r;
                int col = cb + w * 64 + nt * 16 + rsub;
                P[(size_t)row * S + col] = pacc[mt][nt][r];
            }
}

// ---------------------------------------------------------------------------
// acc_init: acc[c] = (c<256 ? sum_{t<256} P[t][c] : 0) + (c<=256 ? P[256][c] : 0)
// ---------------------------------------------------------------------------
__global__ __launch_bounds__(256) void acc_init_kernel(const float* __restrict__ P,
                                                       float* __restrict__ acc_init)
{
    int c = blockIdx.x * 256 + threadIdx.x;
    float s = 0.f;
    if (c < 256) {
        const float* p = P + c;
        float s0 = 0.f, s1 = 0.f, s2 = 0.f, s3 = 0.f;
#pragma unroll 4
        for (int t = 0; t < 256; t += 4) {
            s0 += p[(size_t)t * S];
            s1 += p[(size_t)(t + 1) * S];
            s2 += p[(size_t)(t + 2) * S];
            s3 += p[(size_t)(t + 3) * S];
        }
        s = (s0 + s1) + (s2 + s3);
    }
    if (c <= 256) s += P[(size_t)256 * S + c];
    acc_init[c] = s;
}

// ---------------------------------------------------------------------------
// Sequential heavy-hitter scan — single wave, no producers, no volatiles.
// Heavy (col,val) in registers (2/lane). All step-t+1 inputs prefetched one
// full iteration ahead (loop-carried): streams have known addresses; the two
// scattered gathers are covered speculatively (c0' ∈ {c0, newc}), selected
// after the eviction decision. Argmin uses packed u64 (valbits<<32 | ~col):
// unsigned min == (min value, tie -> larger col evicted), and comparing with
// pack(nv,newc) reproduces the strict mv<nv new-column tie-break exactly.
// ---------------------------------------------------------------------------
__global__ void scan_kernel(const float* __restrict__ P,
                            const float* __restrict__ acc_init,
                            unsigned short* __restrict__ heavy)
{
    __shared__ float accL[S];      // 8 KB
    const int lane = threadIdx.x;  // 64 threads = 1 wave

    for (int c = lane; c < S; c += 64) accL[c] = acc_init[c];

    heavy[START_T * HEAVY_K + lane] = (unsigned short)lane;
    heavy[START_T * HEAVY_K + 64 + lane] = (unsigned short)(lane + 64);

    int   c0 = lane, c1 = lane + 64;
    float v0 = acc_init[lane], v1 = acc_init[lane + 64];

    // prefetch state for t=257 (as if issued "during step 256")
    float A0p, A1p, AXp, SR0p, SR1p, STp, SNp;
    {
        const float* Pn = P + (size_t)257 * S;
        A0p  = Pn[c0];
        A1p  = Pn[c1];
        AXp  = Pn[127];          // unused (no eviction preceded t=257)
        SR0p = Pn[129 + lane];   // window(257) = [129, 257]
        SR1p = Pn[193 + lane];
        STp  = Pn[257];
        SNp  = Pn[128];          // pnew(257), newc(257)=128
    }
    float AR0p = accL[129 + lane];
    float AR1p = accL[193 + lane];
    float ANp  = accL[128];      // nv(257)
    bool e0p = false, e1p = false;

    for (int t = START_T + 1; t < S; ++t) {
        // ---- phase 1: issue global prefetch for step t+1 (current c0,c1) ----
        const int tn = (t + 1 < S) ? (t + 1) : (S - 1);
        const float* Pn = P + (size_t)tn * S;
        float nA0  = Pn[c0];
        float nA1  = Pn[c1];
        float nAX  = Pn[tn - 130];          // P[t+1][newc(t)]
        float nSR0 = Pn[tn - 128 + lane];
        float nSR1 = Pn[tn - 64 + lane];
        float nST  = Pn[tn];
        float nSN  = Pn[tn - 129];          // pnew(t+1)

        // ---- phase 2: argmin over 128 register-resident heavy (packed u64) --
        unsigned long long p0 = ((unsigned long long)__float_as_uint(v0) << 32) | (unsigned)(~c0);
        unsigned long long p1 = ((unsigned long long)__float_as_uint(v1) << 32) | (unsigned)(~c1);
        unsigned long long m = (p1 < p0) ? p1 : p0;
#pragma unroll
        for (int off = 1; off < 64; off <<= 1) {
            unsigned long long om = __shfl_xor(m, off);
            if (om < m) m = om;
        }

        // ---- phase 3: eviction decision vs new column ----
        const int newc = t - 129;
        const float nv = ANp;
        unsigned long long pn = ((unsigned long long)__float_as_uint(nv) << 32) | (unsigned)(~newc);
        const bool evict = (m < pn);        // tie -> new col dropped
        const int mc = (int)(~(unsigned)m); // low 32 bits -> evicted col

        // ---- phase 4: update heavy state (selects use prev-iter loads) ----
        float pv0 = e0p ? AXp : A0p;
        float pv1 = e1p ? AXp : A1p;
        bool e0 = evict && (c0 == mc);
        bool e1 = evict && (c1 == mc);
        v0 = e0 ? (nv + SNp) : (v0 + pv0);
        c0 = e0 ? newc : c0;
        v1 = e1 ? (nv + SNp) : (v1 + pv1);
        c1 = e1 ? newc : c1;

        heavy[(size_t)t * HEAVY_K + lane]      = (unsigned short)c0;
        heavy[(size_t)t * HEAVY_K + 64 + lane] = (unsigned short)c1;

        // ---- phase 5: recent-window accumulate (LDS) ----
        accL[t - 128 + lane] = AR0p + SR0p;
        accL[t - 64 + lane]  = AR1p + SR1p;
        if (lane == 0) accL[t] = STp;       // col t first touched at step t

        // ---- phase 6: LDS prefetch for t+1 (after this step's writes) ----
        AR0p = accL[tn - 128 + lane];
        AR1p = accL[tn - 64 + lane];
        ANp  = accL[tn - 129];

        // ---- rotate loop-carried prefetch registers ----
        A0p = nA0; A1p = nA1; AXp = nAX;
        SR0p = nSR0; SR1p = nSR1; STp = nST; SNp = nSN;
        e0p = e0; e1p = e1;
    }
}

// ---------------------------------------------------------------------------
// Sparse masked attention: row t attends to {128 heavy} ∪ [t-128, t]
// ---------------------------------------------------------------------------
__global__ __launch_bounds__(256) void attn_kernel(const unsigned short* __restrict__ qb,
                                                   const unsigned short* __restrict__ kb,
                                                   const float* __restrict__ v,
                                                   const unsigned short* __restrict__ heavy,
                                                   float* __restrict__ attn)
{
    const int t = blockIdx.x;
    const int tid = threadIdx.x;
    __shared__ float qs[HDIM];
    __shared__ float sc[NH][258];
    __shared__ unsigned short cols[260];
    __shared__ float zpart[NH][8];
    __shared__ float zf[NH];
    const int cnt = (t < START_T) ? (t + 1) : 257;
    {
        const short8* qr = (const short8*)(qb + (size_t)t * HDIM);
        short8 qv = qr[tid];
#pragma unroll
        for (int j = 0; j < 8; ++j) qs[tid * 8 + j] = bf2f((unsigned short)qv[j]);
    }
    if (t < START_T) {
        for (int j = tid; j < cnt; j += 256) cols[j] = (unsigned short)j;
    } else {
        if (tid < 128) cols[tid] = heavy[(size_t)t * HEAVY_K + tid];
        else           cols[tid] = (unsigned short)(t - 256 + tid);
        if (tid == 0)  cols[256] = (unsigned short)t;
    }
    __syncthreads();
    {
        const int h = tid & 31;
        const float* qh = qs + h * HD;
        for (int j = tid >> 5; j < cnt; j += 8) {
            const short8* kc8 = (const short8*)(kb + (size_t)cols[j] * HD);
            float s = 0.f;
#pragma unroll
            for (int dq = 0; dq < 8; ++dq) {
                short8 kv = kc8[dq];
#pragma unroll
                for (int e = 0; e < 8; ++e)
                    s += qh[dq * 8 + e] * bf2f((unsigned short)kv[e]);
            }
            sc[h][j] = s * 0.125f;
        }
    }
    __syncthreads();
    {
        const int h2 = tid >> 3, sub = tid & 7;
        float z = 0.f;
        for (int j = sub; j < cnt; j += 8) {
            float e = __expf(sc[h2][j]);
            sc[h2][j] = e;
            z += e;
        }
        zpart[h2][sub] = z;
    }
    __syncthreads();
    if (tid < NH) {
        float z = 0.f;
#pragma unroll
        for (int s2 = 0; s2 < 8; ++s2) z += zpart[tid][s2];
        zf[tid] = 1.0f / z;
    }
    __syncthreads();
    {
        const int h2 = tid >> 3;
        const int dbase = (tid & 7) * 8;
        float o[8] = {0, 0, 0, 0, 0, 0, 0, 0};
        for (int j = 0; j < cnt; ++j) {
            float p = sc[h2][j];
            const float* vc = v + (size_t)cols[j] * HD + dbase;
            float4 va = *(const float4*)vc;
            float4 vb = *(const float4*)(vc + 4);
            o[0] += p * va.x; o[1] += p * va.y; o[2] += p * va.z; o[3] += p * va.w;
            o[4] += p * vb.x; o[5] += p * vb.y; o[6] += p * vb.z; o[7] += p * vb.w;
        }
        float zi = zf[h2];
        float* op = attn + (size_t)t * HDIM + h2 * HD + dbase;
        float4 ra = make_float4(o[0] * zi, o[1] * zi, o[2] * zi, o[3] * zi);
        float4 rb = make_float4(o[4] * zi, o[5] * zi, o[6] * zi, o[7] * zi);
        *(float4*)op = ra;
        *(float4*)(op + 4) = rb;
    }
}

// ---------------------------------------------------------------------------
extern "C" void kernel_launch(void* const* d_in, const int* in_sizes, int n_in,
                              void* d_out, int out_size, void* d_ws, size_t ws_size,
                              hipStream_t stream)
{
    (void)in_sizes; (void)n_in; (void)out_size; (void)ws_size;
    const float* hs      = (const float*)d_in[0];
    const float* w_qkv   = (const float*)d_in[1];
    const float* w_dense = (const float*)d_in[2];
    float* out = (float*)d_out;
    char* ws = (char*)d_ws;

    // workspace layout (bytes):
    //   [0, 17825792)            fused (2048x2176 f32) -> P (2048x2048 f32) -> attn (2048x2048 f32)
    //   [17825792, 26214400)     qb  bf16 [2048][2048]
    //   [26214400, 26476544)     kb  bf16 [2048][64]
    //   [26476544, 27000832)     v   f32  [2048][64]
    //   [27000832, 27262976)     zinv f32 [2048][32]
    //   [27262976, 27787264)     heavy ushort [2048][128]
    //   [27787264, 27795456)     acc_init f32 [2048]
    float* fused = (float*)(ws);
    float* P     = (float*)(ws);
    float* attn  = (float*)(ws);
    unsigned short* qb = (unsigned short*)(ws + 17825792);
    unsigned short* kb = (unsigned short*)(ws + 26214400);
    float* v           = (float*)(ws + 26476544);
    float* zinv        = (float*)(ws + 27000832);
    unsigned short* heavy = (unsigned short*)(ws + 27262976);
    float* acc_init       = (float*)(ws + 27787264);

    dim3 g1(FUSED_N / 64, S / 128);
    gemm_nt_kernel<<<g1, 256, 0, stream>>>(hs, w_qkv, fused, HDIM, FUSED_N);

    int total = S * NJ * HD;
    rope_split_kernel<<<(total + 255) / 256, 256, 0, stream>>>(fused, qb, kb, v);

    dim3 gz(S / 32, NH);
    z_kernel<<<gz, 256, 0, stream>>>(qb, kb, zinv);

    dim3 gp(S / 256, S / 32);
    pnorm_kernel<<<gp, 256, 0, stream>>>(qb, kb, zinv, P);

    acc_init_kernel<<<S / 256, 256, 0, stream>>>(P, acc_init);

    scan_kernel<<<1, 64, 0, stream>>>(P, acc_init, heavy);

    attn_kernel<<<S, 256, 0, stream>>>(qb, kb, v, heavy, attn);

    dim3 g2(HDIM / 64, S / 128);
    gemm_nt_kernel<<<g2, 256, 0, stream>>>(attn, w_dense, out, HDIM, HDIM);
}

// Round 6
// 1351.241 us; speedup vs baseline: 2.7084x; 1.3980x over previous
//
#include <hip/hip_runtime.h>
#include <hip/hip_bf16.h>
#include <cstdint>

#define S 2048
#define NH 32
#define HD 64
#define NJ 34              // 32 q heads + k + v
#define FUSED_N (NJ * HD)  // 2176
#define HDIM (NH * HD)     // 2048
#define HEAVY_K 128
#define RECENT_W 128
#define START_T 256

typedef __attribute__((ext_vector_type(8))) short short8;
typedef __attribute__((ext_vector_type(4))) float floatx4;

static __device__ __forceinline__ unsigned short f2bf(float f) {
    unsigned u = __float_as_uint(f);
    unsigned r = (u + 0x7FFF + ((u >> 16) & 1)) >> 16; // round-nearest-even
    return (unsigned short)r;
}
static __device__ __forceinline__ float bf2f(unsigned short b) {
    return __uint_as_float(((unsigned)b) << 16);
}

// ---------------------------------------------------------------------------
// MFMA GEMM with on-the-fly bf16x2 split (near-fp32 accuracy):
// C[M][N] = A[M][K] * B[N][K]^T ; A,B f32; C f32.
// A = Ah + Al (bf16 each); C += Ah·Bh + Ah·Bl + Al·Bh  (drop Al·Bl, ~2^-18)
// tile 128x128, BK=32, 256 threads = 4 waves; wave: 32 rows x 128 cols.
// Fragment layout identical to the verified z/pnorm kernels.
// ---------------------------------------------------------------------------
#define GBM 128
#define GBN 128
#define GBK 32
__global__ __launch_bounds__(256) void gemm_nt_mfma(const float* __restrict__ A,
                                                    const float* __restrict__ B,
                                                    float* __restrict__ C,
                                                    int M, int N, int K)
{
    __shared__ unsigned short Ash[GBM][GBK + 8], Asl[GBM][GBK + 8];
    __shared__ unsigned short Bsh[GBN][GBK + 8], Bsl[GBN][GBK + 8];
    const int bm = blockIdx.y * GBM;
    const int bn = blockIdx.x * GBN;
    const int tid = threadIdx.x;
    const int w = tid >> 6, lane = tid & 63;
    const int rsub = lane & 15;
    const int d0 = (lane >> 4) * 8;

    floatx4 acc[2][8] = {};

    for (int k0 = 0; k0 < K; k0 += GBK) {
        // ---- stage A,B tiles: f32 -> (hi,lo) bf16 in LDS ----
#pragma unroll
        for (int i = 0; i < 4; ++i) {
            int l = tid + i * 256;           // 0..1023
            int r = l >> 3;                  // row 0..127
            int kq = (l & 7) * 4;            // k 0..28
            float4 xa = *(const float4*)&A[(size_t)(bm + r) * K + k0 + kq];
            float4 xb = *(const float4*)&B[(size_t)(bn + r) * K + k0 + kq];
            ushort4 ah, al, bh, bl;
            ah.x = f2bf(xa.x); al.x = f2bf(xa.x - bf2f(ah.x));
            ah.y = f2bf(xa.y); al.y = f2bf(xa.y - bf2f(ah.y));
            ah.z = f2bf(xa.z); al.z = f2bf(xa.z - bf2f(ah.z));
            ah.w = f2bf(xa.w); al.w = f2bf(xa.w - bf2f(ah.w));
            bh.x = f2bf(xb.x); bl.x = f2bf(xb.x - bf2f(bh.x));
            bh.y = f2bf(xb.y); bl.y = f2bf(xb.y - bf2f(bh.y));
            bh.z = f2bf(xb.z); bl.z = f2bf(xb.z - bf2f(bh.z));
            bh.w = f2bf(xb.w); bl.w = f2bf(xb.w - bf2f(bh.w));
            *(ushort4*)&Ash[r][kq] = ah;
            *(ushort4*)&Asl[r][kq] = al;
            *(ushort4*)&Bsh[r][kq] = bh;
            *(ushort4*)&Bsl[r][kq] = bl;
        }
        __syncthreads();

        short8 a_h[2], a_l[2];
#pragma unroll
        for (int mt = 0; mt < 2; ++mt) {
            const int row = w * 32 + mt * 16 + rsub;
            a_h[mt] = *(const short8*)&Ash[row][d0];
            a_l[mt] = *(const short8*)&Asl[row][d0];
        }
#pragma unroll
        for (int nt = 0; nt < 8; ++nt) {
            const int col = nt * 16 + rsub;
            short8 b_h = *(const short8*)&Bsh[col][d0];
            short8 b_l = *(const short8*)&Bsl[col][d0];
#pragma unroll
            for (int mt = 0; mt < 2; ++mt) {
                acc[mt][nt] = __builtin_amdgcn_mfma_f32_16x16x32_bf16(a_l[mt], b_h, acc[mt][nt], 0, 0, 0);
                acc[mt][nt] = __builtin_amdgcn_mfma_f32_16x16x32_bf16(a_h[mt], b_l, acc[mt][nt], 0, 0, 0);
                acc[mt][nt] = __builtin_amdgcn_mfma_f32_16x16x32_bf16(a_h[mt], b_h, acc[mt][nt], 0, 0, 0);
            }
        }
        __syncthreads();
    }
#pragma unroll
    for (int mt = 0; mt < 2; ++mt) {
        const int orow = bm + w * 32 + mt * 16 + (lane >> 4) * 4;
#pragma unroll
        for (int nt = 0; nt < 8; ++nt) {
            const int ocol = bn + nt * 16 + rsub;
#pragma unroll
            for (int r = 0; r < 4; ++r)
                C[(size_t)(orow + r) * N + ocol] = acc[mt][nt][r];
        }
    }
}

// ---------------------------------------------------------------------------
// RoPE + split fused -> qb [S][2048] bf16, kb [S][64] bf16, v [S][64] f32
// ---------------------------------------------------------------------------
__global__ __launch_bounds__(256) void rope_split_kernel(const float* __restrict__ fused,
                                                         unsigned short* __restrict__ qb,
                                                         unsigned short* __restrict__ kb,
                                                         float* __restrict__ v)
{
    int idx = blockIdx.x * 256 + threadIdx.x;
    const int total = S * NJ * HD;
    if (idx >= total) return;
    int t = idx / FUSED_N;
    int rem = idx - t * FUSED_N;
    int j = rem >> 6;
    int d = rem & 63;
    float x = fused[idx];
    if (j == 33) { v[t * HD + d] = x; return; }
    int i = d & 31;
    double inv = exp2(-(double)i * (13.287712379549449 / 32.0)); // 10000^(-i/32)
    double ang = (double)t * inv;
    float c  = (float)cos(ang);
    float sn = (float)sin(ang);
    float xo = fused[idx - d + ((d < 32) ? (d + 32) : (d - 32))];
    float rot = (d < 32) ? -xo : xo;
    unsigned short outv = f2bf(x * c + rot * sn);
    if (j == 32) kb[t * HD + d] = outv;
    else         qb[(size_t)t * HDIM + j * HD + d] = outv;
}

// ---------------------------------------------------------------------------
// z_kernel: Zinv[t][h] = 1 / sum_c exp(q_h[t]·k[c]/8)
// ---------------------------------------------------------------------------
__global__ __launch_bounds__(256) void z_kernel(const unsigned short* __restrict__ qb,
                                                const unsigned short* __restrict__ kb,
                                                float* __restrict__ zinv)
{
    const int t0 = blockIdx.x * 32;
    const int h  = blockIdx.y;
    const int w    = threadIdx.x >> 6;
    const int lane = threadIdx.x & 63;
    const int rsub = lane & 15;
    const int d0   = (lane >> 4) * 8;
    __shared__ float zl[4][32];

    short8 a[2][2];
#pragma unroll
    for (int mt = 0; mt < 2; ++mt) {
        const short8* ap = (const short8*)(qb + (size_t)(t0 + mt * 16 + rsub) * HDIM + h * HD + d0);
        a[mt][0] = ap[0];
        a[mt][1] = ap[4];
    }
    float z[2][4] = {};
    for (int nt = 0; nt < 32; ++nt) {
        const int c = w * 512 + nt * 16 + rsub;
        const short8* bp = (const short8*)(kb + (size_t)c * HD + d0);
        short8 b0 = bp[0];
        short8 b1 = bp[4];
#pragma unroll
        for (int mt = 0; mt < 2; ++mt) {
            floatx4 acc = {0.f, 0.f, 0.f, 0.f};
            acc = __builtin_amdgcn_mfma_f32_16x16x32_bf16(a[mt][0], b0, acc, 0, 0, 0);
            acc = __builtin_amdgcn_mfma_f32_16x16x32_bf16(a[mt][1], b1, acc, 0, 0, 0);
#pragma unroll
            for (int r = 0; r < 4; ++r) z[mt][r] += __expf(acc[r] * 0.125f);
        }
    }
#pragma unroll
    for (int mt = 0; mt < 2; ++mt)
#pragma unroll
        for (int r = 0; r < 4; ++r) {
            float zz = z[mt][r];
#pragma unroll
            for (int off = 1; off < 16; off <<= 1) zz += __shfl_xor(zz, off);
            z[mt][r] = zz;
        }
    if (rsub == 0) {
#pragma unroll
        for (int mt = 0; mt < 2; ++mt)
#pragma unroll
            for (int r = 0; r < 4; ++r)
                zl[w][mt * 16 + (lane >> 4) * 4 + r] = z[mt][r];
    }
    __syncthreads();
    if (threadIdx.x < 32) {
        float s = zl[0][threadIdx.x] + zl[1][threadIdx.x] + zl[2][threadIdx.x] + zl[3][threadIdx.x];
        zinv[(size_t)(t0 + threadIdx.x) * NH + h] = 1.0f / s;
    }
}

// ---------------------------------------------------------------------------
// pnorm_kernel: P[t][c] = sum_h exp(q_h[t]·k[c]/8) * zinv[t][h]
// ---------------------------------------------------------------------------
__global__ __launch_bounds__(256) void pnorm_kernel(const unsigned short* __restrict__ qb,
                                                    const unsigned short* __restrict__ kb,
                                                    const float* __restrict__ zinv,
                                                    float* __restrict__ P)
{
    const int t0 = blockIdx.y * 32;
    const int cb = blockIdx.x * 256;
    const int w    = threadIdx.x >> 6;
    const int lane = threadIdx.x & 63;
    const int rsub = lane & 15;
    const int d0   = (lane >> 4) * 8;
    __shared__ float zi[32][33];
    for (int i = threadIdx.x; i < 32 * 32; i += 256) {
        int row = i >> 5, hh = i & 31;
        zi[row][hh] = zinv[(size_t)(t0 + row) * NH + hh];
    }
    __syncthreads();

    float pacc[2][4][4] = {};
    for (int h = 0; h < NH; ++h) {
        short8 a[2][2];
#pragma unroll
        for (int mt = 0; mt < 2; ++mt) {
            const short8* ap = (const short8*)(qb + (size_t)(t0 + mt * 16 + rsub) * HDIM + h * HD + d0);
            a[mt][0] = ap[0];
            a[mt][1] = ap[4];
        }
        float zv[2][4];
#pragma unroll
        for (int mt = 0; mt < 2; ++mt)
#pragma unroll
            for (int r = 0; r < 4; ++r)
                zv[mt][r] = zi[mt * 16 + (lane >> 4) * 4 + r][h];
#pragma unroll
        for (int nt = 0; nt < 4; ++nt) {
            const int c = cb + w * 64 + nt * 16 + rsub;
            const short8* bp = (const short8*)(kb + (size_t)c * HD + d0);
            short8 b0 = bp[0];
            short8 b1 = bp[4];
#pragma unroll
            for (int mt = 0; mt < 2; ++mt) {
                floatx4 acc = {0.f, 0.f, 0.f, 0.f};
                acc = __builtin_amdgcn_mfma_f32_16x16x32_bf16(a[mt][0], b0, acc, 0, 0, 0);
                acc = __builtin_amdgcn_mfma_f32_16x16x32_bf16(a[mt][1], b1, acc, 0, 0, 0);
#pragma unroll
                for (int r = 0; r < 4; ++r)
                    pacc[mt][nt][r] += __expf(acc[r] * 0.125f) * zv[mt][r];
            }
        }
    }
#pragma unroll
    for (int mt = 0; mt < 2; ++mt)
#pragma unroll
        for (int nt = 0; nt < 4; ++nt)
#pragma unroll
            for (int r = 0; r < 4; ++r) {
                int row = t0 + mt * 16 + (lane >> 4) * 4 + r;
                int col = cb + w * 64 + nt * 16 + rsub;
                P[(size_t)row * S + col] = pacc[mt][nt][r];
            }
}

// ---------------------------------------------------------------------------
// acc_init: acc[c] = (c<256 ? sum_{t<256} P[t][c] : 0) + (c<=256 ? P[256][c] : 0)
// ---------------------------------------------------------------------------
__global__ __launch_bounds__(256) void acc_init_kernel(const float* __restrict__ P,
                                                       float* __restrict__ acc_init)
{
    int c = blockIdx.x * 256 + threadIdx.x;
    float s = 0.f;
    if (c < 256) {
        const float* p = P + c;
        float s0 = 0.f, s1 = 0.f, s2 = 0.f, s3 = 0.f;
#pragma unroll 4
        for (int t = 0; t < 256; t += 4) {
            s0 += p[(size_t)t * S];
            s1 += p[(size_t)(t + 1) * S];
            s2 += p[(size_t)(t + 2) * S];
            s3 += p[(size_t)(t + 3) * S];
        }
        s = (s0 + s1) + (s2 + s3);
    }
    if (c <= 256) s += P[(size_t)256 * S + c];
    acc_init[c] = s;
}

// ---------------------------------------------------------------------------
// Sequential heavy-hitter scan — single wave, VALU/DPP reduce (no LDS on the
// decision chain). Heavy (col,val) in registers (2/lane). Nonneg f32 order ==
// u32 order, so min-reduce runs on u32 via update_dpp(row_shr 1/2/4/8) +
// readlane row-mins. Column of the min: ballot + readlane (unique-bit fast
// path); exact packed-u64 shfl chain on rare ties. Decision semantics are
// bit-identical to the reference (evict iff mv<nv strictly; heavy-internal
// ties evict the larger column).
// ---------------------------------------------------------------------------
template <int CTRL>
static __device__ __forceinline__ unsigned dppmin(unsigned x)
{
    int t = __builtin_amdgcn_update_dpp((int)x, (int)x, CTRL, 0xf, 0xf, false);
    unsigned u = (unsigned)t;
    return x < u ? x : u;
}

__global__ void scan_kernel(const float* __restrict__ P,
                            const float* __restrict__ acc_init,
                            unsigned short* __restrict__ heavy)
{
    __shared__ float accL[S];      // 8 KB
    const int lane = threadIdx.x;  // 64 threads = 1 wave

    for (int c = lane; c < S; c += 64) accL[c] = acc_init[c];

    heavy[START_T * HEAVY_K + lane] = (unsigned short)lane;
    heavy[START_T * HEAVY_K + 64 + lane] = (unsigned short)(lane + 64);

    int   c0 = lane, c1 = lane + 64;
    float v0 = acc_init[lane], v1 = acc_init[lane + 64];

    // prefetch state for t=257
    float A0p, A1p, AXp, SR0p, SR1p, STp, SNp;
    {
        const float* Pn = P + (size_t)257 * S;
        A0p  = Pn[c0];
        A1p  = Pn[c1];
        AXp  = Pn[127];          // unused (no eviction preceded t=257)
        SR0p = Pn[129 + lane];   // window(257) = [129, 257]
        SR1p = Pn[193 + lane];
        STp  = Pn[257];
        SNp  = Pn[128];          // pnew(257), newc(257)=128
    }
    float AR0p = accL[129 + lane];
    float AR1p = accL[193 + lane];
    float nvp  = acc_init[128];  // nv(257), wave-uniform
    bool e0p = false, e1p = false;

    for (int t = START_T + 1; t < S; ++t) {
        // ---- phase 1: issue global prefetch for step t+1 (current c0,c1) ----
        const int tn = (t + 1 < S) ? (t + 1) : (S - 1);
        const float* Pn = P + (size_t)tn * S;
        float nA0  = Pn[c0];
        float nA1  = Pn[c1];
        float nAX  = Pn[tn - 130];          // P[t+1][newc(t)]
        float nSR0 = Pn[tn - 128 + lane];
        float nSR1 = Pn[tn - 64 + lane];
        float nST  = Pn[tn];
        float nSN  = Pn[tn - 129];          // pnew(t+1)

        // ---- phase 2: min-value reduce on VALU (DPP) ----
        unsigned b0 = __float_as_uint(v0), b1 = __float_as_uint(v1);
        unsigned xv = b0 < b1 ? b0 : b1;
        xv = dppmin<0x111>(xv);             // row_shr:1
        xv = dppmin<0x112>(xv);             // row_shr:2
        xv = dppmin<0x114>(xv);             // row_shr:4
        xv = dppmin<0x118>(xv);             // row_shr:8
        unsigned r15 = (unsigned)__builtin_amdgcn_readlane((int)xv, 15);
        unsigned r31 = (unsigned)__builtin_amdgcn_readlane((int)xv, 31);
        unsigned r47 = (unsigned)__builtin_amdgcn_readlane((int)xv, 47);
        unsigned r63 = (unsigned)__builtin_amdgcn_readlane((int)xv, 63);
        unsigned ma = r15 < r31 ? r15 : r31;
        unsigned mb = r47 < r63 ? r47 : r63;
        unsigned mvb = ma < mb ? ma : mb;   // uniform min value (bits)

        // ---- phase 3: column of the min ----
        unsigned long long m0 = __ballot(b0 == mvb);
        unsigned long long m1 = __ballot(b1 == mvb);
        int mc;
        if (__popcll(m0) + __popcll(m1) == 1) {   // unique (common)
            mc = m0 ? __builtin_amdgcn_readlane(c0, __ffsll((unsigned long long)m0) - 1)
                    : __builtin_amdgcn_readlane(c1, __ffsll((unsigned long long)m1) - 1);
        } else {                                   // rare exact tie: packed chain
            unsigned long long p0 = ((unsigned long long)b0 << 32) | (unsigned)(~c0);
            unsigned long long p1 = ((unsigned long long)b1 << 32) | (unsigned)(~c1);
            unsigned long long mm = p1 < p0 ? p1 : p0;
#pragma unroll
            for (int off = 1; off < 64; off <<= 1) {
                unsigned long long om = __shfl_xor(mm, off);
                if (om < mm) mm = om;
            }
            mc = (int)(~(unsigned)mm);
        }

        // ---- phase 4: eviction decision + heavy update ----
        const int newc = t - 129;
        const bool evict = mvb < __float_as_uint(nvp);   // strict; ties keep heavy
        float pv0 = e0p ? AXp : A0p;
        float pv1 = e1p ? AXp : A1p;
        bool e0 = evict && (c0 == mc);
        bool e1 = evict && (c1 == mc);
        v0 = e0 ? (nvp + SNp) : (v0 + pv0);
        c0 = e0 ? newc : c0;
        v1 = e1 ? (nvp + SNp) : (v1 + pv1);
        c1 = e1 ? newc : c1;

        heavy[(size_t)t * HEAVY_K + lane]      = (unsigned short)c0;
        heavy[(size_t)t * HEAVY_K + 64 + lane] = (unsigned short)c1;

        // ---- phase 5: recent-window accumulate (LDS, off decision chain) ----
        float w0 = AR0p + SR0p;
        float w1 = AR1p + SR1p;
        accL[t - 128 + lane] = w0;
        accL[t - 64 + lane]  = w1;
        if (lane == 0) accL[t] = STp;       // col t first touched at step t

        // nv(t+1) = accL[t-128] = lane0's w0 — broadcast via readlane (no LDS)
        nvp = __uint_as_float((unsigned)__builtin_amdgcn_readlane((int)__float_as_uint(w0), 0));

        // ---- phase 6: LDS prefetch for t+1 (full iteration of slack) ----
        AR0p = accL[tn - 128 + lane];
        AR1p = accL[tn - 64 + lane];

        // ---- rotate loop-carried prefetch registers ----
        A0p = nA0; A1p = nA1; AXp = nAX;
        SR0p = nSR0; SR1p = nSR1; STp = nST; SNp = nSN;
        e0p = e0; e1p = e1;
    }
}

// ---------------------------------------------------------------------------
// Sparse masked attention: row t attends to {128 heavy} ∪ [t-128, t]
// ---------------------------------------------------------------------------
__global__ __launch_bounds__(256) void attn_kernel(const unsigned short* __restrict__ qb,
                                                   const unsigned short* __restrict__ kb,
                                                   const float* __restrict__ v,
                                                   const unsigned short* __restrict__ heavy,
                                                   float* __restrict__ attn)
{
    const int t = blockIdx.x;
    const int tid = threadIdx.x;
    __shared__ float qs[HDIM];
    __shared__ float sc[NH][258];
    __shared__ unsigned short cols[260];
    __shared__ float zpart[NH][8];
    __shared__ float zf[NH];
    const int cnt = (t < START_T) ? (t + 1) : 257;
    {
        const short8* qr = (const short8*)(qb + (size_t)t * HDIM);
        short8 qv = qr[tid];
#pragma unroll
        for (int j = 0; j < 8; ++j) qs[tid * 8 + j] = bf2f((unsigned short)qv[j]);
    }
    if (t < START_T) {
        for (int j = tid; j < cnt; j += 256) cols[j] = (unsigned short)j;
    } else {
        if (tid < 128) cols[tid] = heavy[(size_t)t * HEAVY_K + tid];
        else           cols[tid] = (unsigned short)(t - 256 + tid);
        if (tid == 0)  cols[256] = (unsigned short)t;
    }
    __syncthreads();
    {
        const int h = tid & 31;
        const float* qh = qs + h * HD;
        for (int j = tid >> 5; j < cnt; j += 8) {
            const short8* kc8 = (const short8*)(kb + (size_t)cols[j] * HD);
            float s = 0.f;
#pragma unroll
            for (int dq = 0; dq < 8; ++dq) {
                short8 kv = kc8[dq];
#pragma unroll
                for (int e = 0; e < 8; ++e)
                    s += qh[dq * 8 + e] * bf2f((unsigned short)kv[e]);
            }
            sc[h][j] = s * 0.125f;
        }
    }
    __syncthreads();
    {
        const int h2 = tid >> 3, sub = tid & 7;
        float z = 0.f;
        for (int j = sub; j < cnt; j += 8) {
            float e = __expf(sc[h2][j]);
            sc[h2][j] = e;
            z += e;
        }
        zpart[h2][sub] = z;
    }
    __syncthreads();
    if (tid < NH) {
        float z = 0.f;
#pragma unroll
        for (int s2 = 0; s2 < 8; ++s2) z += zpart[tid][s2];
        zf[tid] = 1.0f / z;
    }
    __syncthreads();
    {
        const int h2 = tid >> 3;
        const int dbase = (tid & 7) * 8;
        float o[8] = {0, 0, 0, 0, 0, 0, 0, 0};
        for (int j = 0; j < cnt; ++j) {
            float p = sc[h2][j];
            const float* vc = v + (size_t)cols[j] * HD + dbase;
            float4 va = *(const float4*)vc;
            float4 vb = *(const float4*)(vc + 4);
            o[0] += p * va.x; o[1] += p * va.y; o[2] += p * va.z; o[3] += p * va.w;
            o[4] += p * vb.x; o[5] += p * vb.y; o[6] += p * vb.z; o[7] += p * vb.w;
        }
        float zi = zf[h2];
        float* op = attn + (size_t)t * HDIM + h2 * HD + dbase;
        float4 ra = make_float4(o[0] * zi, o[1] * zi, o[2] * zi, o[3] * zi);
        float4 rb = make_float4(o[4] * zi, o[5] * zi, o[6] * zi, o[7] * zi);
        *(float4*)op = ra;
        *(float4*)(op + 4) = rb;
    }
}

// ---------------------------------------------------------------------------
extern "C" void kernel_launch(void* const* d_in, const int* in_sizes, int n_in,
                              void* d_out, int out_size, void* d_ws, size_t ws_size,
                              hipStream_t stream)
{
    (void)in_sizes; (void)n_in; (void)out_size; (void)ws_size;
    const float* hs      = (const float*)d_in[0];
    const float* w_qkv   = (const float*)d_in[1];
    const float* w_dense = (const float*)d_in[2];
    float* out = (float*)d_out;
    char* ws = (char*)d_ws;

    // workspace layout (bytes):
    //   [0, 17825792)            fused (2048x2176 f32) -> P (2048x2048 f32) -> attn (2048x2048 f32)
    //   [17825792, 26214400)     qb  bf16 [2048][2048]
    //   [26214400, 26476544)     kb  bf16 [2048][64]
    //   [26476544, 27000832)     v   f32  [2048][64]
    //   [27000832, 27262976)     zinv f32 [2048][32]
    //   [27262976, 27787264)     heavy ushort [2048][128]
    //   [27787264, 27795456)     acc_init f32 [2048]
    float* fused = (float*)(ws);
    float* P     = (float*)(ws);
    float* attn  = (float*)(ws);
    unsigned short* qb = (unsigned short*)(ws + 17825792);
    unsigned short* kb = (unsigned short*)(ws + 26214400);
    float* v           = (float*)(ws + 26476544);
    float* zinv        = (float*)(ws + 27000832);
    unsigned short* heavy = (unsigned short*)(ws + 27262976);
    float* acc_init       = (float*)(ws + 27787264);

    dim3 g1(FUSED_N / GBN, S / GBM);     // (17, 16)
    gemm_nt_mfma<<<g1, 256, 0, stream>>>(hs, w_qkv, fused, S, FUSED_N, HDIM);

    int total = S * NJ * HD;
    rope_split_kernel<<<(total + 255) / 256, 256, 0, stream>>>(fused, qb, kb, v);

    dim3 gz(S / 32, NH);
    z_kernel<<<gz, 256, 0, stream>>>(qb, kb, zinv);

    dim3 gp(S / 256, S / 32);
    pnorm_kernel<<<gp, 256, 0, stream>>>(qb, kb, zinv, P);

    acc_init_kernel<<<S / 256, 256, 0, stream>>>(P, acc_init);

    scan_kernel<<<1, 64, 0, stream>>>(P, acc_init, heavy);

    attn_kernel<<<S, 256, 0, stream>>>(qb, kb, v, heavy, attn);

    dim3 g2(HDIM / GBN, S / GBM);        // (16, 16)
    gemm_nt_mfma<<<g2, 256, 0, stream>>>(attn, w_dense, out, S, HDIM, HDIM);
}